// Round 2
// baseline (877.287 us; speedup 1.0000x reference)
//
#include <hip/hip_runtime.h>
#include <hip/hip_bf16.h>

typedef __bf16 bf16;
typedef __bf16 bf16x8 __attribute__((ext_vector_type(8)));
typedef float f32x4 __attribute__((ext_vector_type(4)));

__device__ __forceinline__ float b2f(bf16 v) { return (float)v; }
__device__ __forceinline__ bf16 f2b(float v) { return (bf16)v; }

__device__ __forceinline__ float wave_sum(float v) {
    #pragma unroll
    for (int o = 32; o; o >>= 1) v += __shfl_xor(v, o);
    return v;
}
__device__ __forceinline__ float wave_max(float v) {
    #pragma unroll
    for (int o = 32; o; o >>= 1) v = fmaxf(v, __shfl_xor(v, o));
    return v;
}
__device__ __forceinline__ float leaky(float x) { return x >= 0.0f ? x : 0.2f * x; }

__device__ __forceinline__ bf16x8 zero8() {
    bf16x8 v;
    #pragma unroll
    for (int j = 0; j < 8; ++j) v[j] = (bf16)0.0f;
    return v;
}

// ---------------- h0 = [x | renorm(gene_table[pos])]  (N x 192, bf16) -------
__global__ void build_h0_kernel(const float* __restrict__ x,
                                const float* __restrict__ gene_table,
                                const int* __restrict__ pos,
                                bf16* __restrict__ h0, int n) {
    int wid = blockIdx.x * 4 + (threadIdx.x >> 6);
    int lane = threadIdx.x & 63;
    if (wid >= n) return;
    const float* g = gene_table + (long long)pos[wid] * 128;
    float p0 = g[lane], p1 = g[lane + 64];
    float ss = wave_sum(p0 * p0 + p1 * p1);
    float nrm = sqrtf(ss);
    float sc = nrm > 1.0f ? 1.0f / (nrm + 1e-7f) : 1.0f;
    bf16* o = h0 + (long long)wid * 192;
    o[lane] = f2b(x[(long long)wid * 64 + lane]);
    o[64 + lane] = f2b(p0 * sc);
    o[128 + lane] = f2b(p1 * sc);
}

// ---------------- GEMM: out = A(N x K, bf16) @ W(K x C, f32) [+bias][relu] --
// KB = ceil(K/32); A rows must be zero-padded to KB*32 cols. NT = C/16.
// Wave handles 32 rows (2 M-tiles), all C cols. out is bf16, stride ldo.
template <int KB, int NT>
__global__ __launch_bounds__(256) void gemm_kernel(
    const bf16* __restrict__ A, int lda,
    const float* __restrict__ W, int Kreal, int Creal,
    const float* __restrict__ bias, int relu,
    bf16* __restrict__ out, int ldo, int nrows) {
    __shared__ __attribute__((aligned(16))) bf16 sW[KB * NT * 512];
    int tid = threadIdx.x;
    // stage W into LDS in B-fragment layout:
    // frag f=(kb,nt,lane): elem j = W[kb*32 + (lane>>4)*8 + j][nt*16 + (lane&15)]
    for (int f = tid; f < KB * NT * 64; f += 256) {
        int kb = f / (NT * 64);
        int rem = f % (NT * 64);
        int nt = rem / 64;
        int ln = rem % 64;
        int q = ln >> 4, m = ln & 15;
        int c = nt * 16 + m;
        #pragma unroll
        for (int j = 0; j < 8; ++j) {
            int k = kb * 32 + q * 8 + j;
            sW[f * 8 + j] = (k < Kreal) ? f2b(W[k * Creal + c]) : (bf16)0.0f;
        }
    }
    __syncthreads();

    int wave = tid >> 6, lane = tid & 63;
    int q = lane >> 4, m = lane & 15;
    long long row_base = (long long)blockIdx.x * 128 + wave * 32;

    f32x4 acc[2][NT];
    #pragma unroll
    for (int t = 0; t < 2; ++t)
        #pragma unroll
        for (int nt = 0; nt < NT; ++nt) {
            f32x4 z = {0.f, 0.f, 0.f, 0.f};
            acc[t][nt] = z;
        }

    for (int kb = 0; kb < KB; ++kb) {
        long long r0 = row_base + m;
        long long r1 = row_base + 16 + m;
        bf16x8 a0 = (r0 < nrows)
            ? *reinterpret_cast<const bf16x8*>(A + r0 * lda + kb * 32 + q * 8)
            : zero8();
        bf16x8 a1 = (r1 < nrows)
            ? *reinterpret_cast<const bf16x8*>(A + r1 * lda + kb * 32 + q * 8)
            : zero8();
        #pragma unroll
        for (int nt = 0; nt < NT; ++nt) {
            bf16x8 b = *reinterpret_cast<const bf16x8*>(&sW[((kb * NT + nt) * 64 + lane) * 8]);
            acc[0][nt] = __builtin_amdgcn_mfma_f32_16x16x32_bf16(a0, b, acc[0][nt], 0, 0, 0);
            acc[1][nt] = __builtin_amdgcn_mfma_f32_16x16x32_bf16(a1, b, acc[1][nt], 0, 0, 0);
        }
    }
    // epilogue: D[row = row_base + t*16 + q*4 + r][col = nt*16 + m]
    #pragma unroll
    for (int t = 0; t < 2; ++t)
        #pragma unroll
        for (int nt = 0; nt < NT; ++nt) {
            int col = nt * 16 + m;
            float bv = bias ? bias[col] : 0.0f;
            #pragma unroll
            for (int r = 0; r < 4; ++r) {
                long long row = row_base + t * 16 + q * 4 + r;
                if (row < nrows) {
                    float v = acc[t][nt][r] + bv;
                    if (relu) v = fmaxf(v, 0.0f);
                    out[row * ldo + col] = f2b(v);
                }
            }
        }
}

// ---------------- asrc/adst = hgat @ a_src, hgat @ a_dst -------------------
__global__ void attn_logits_kernel(const bf16* __restrict__ hgat,
                                   const float* __restrict__ a_src,
                                   const float* __restrict__ a_dst,
                                   float* __restrict__ asrc, float* __restrict__ adst, int n) {
    int wid = blockIdx.x * 4 + (threadIdx.x >> 6);
    int lane = threadIdx.x & 63;
    if (wid >= n) return;
    const bf16* h = hgat + (long long)wid * 128;
    float h0 = b2f(h[lane]), h1 = b2f(h[lane + 64]);
    float s1 = wave_sum(h0 * a_src[lane] + h1 * a_src[lane + 64]);
    float s2 = wave_sum(h0 * a_dst[lane] + h1 * a_dst[lane + 64]);
    if (lane == 0) { asrc[wid] = s1; adst[wid] = s2; }
}

// ---------------- CSR build ------------------------------------------------
__global__ void hist_kernel(const int* __restrict__ dst, int* __restrict__ deg, int e) {
    for (int i = blockIdx.x * blockDim.x + threadIdx.x; i < e; i += gridDim.x * blockDim.x)
        atomicAdd(&deg[dst[i]], 1);
}

__global__ void block_sum_kernel(const int* __restrict__ deg, int* __restrict__ bsum, int n) {
    __shared__ int sd[256];
    int t = threadIdx.x;
    int base = blockIdx.x * 1024;
    int s = 0;
    #pragma unroll
    for (int j = 0; j < 4; ++j) {
        int i = base + j * 256 + t;
        if (i < n) s += deg[i];
    }
    sd[t] = s; __syncthreads();
    #pragma unroll
    for (int off = 128; off; off >>= 1) {
        if (t < off) sd[t] += sd[t + off];
        __syncthreads();
    }
    if (t == 0) bsum[blockIdx.x] = sd[0];
}

__global__ void scan_bsum_kernel(int* __restrict__ bsum, int nb) {
    __shared__ int sd[256];
    int t = threadIdx.x;
    int v = (t < nb) ? bsum[t] : 0;
    sd[t] = v; __syncthreads();
    for (int off = 1; off < 256; off <<= 1) {
        int tv = (t >= off) ? sd[t - off] : 0;
        __syncthreads();
        sd[t] += tv;
        __syncthreads();
    }
    if (t < nb) bsum[t] = sd[t] - v;  // exclusive
}

__global__ void scan_final_kernel(const int* __restrict__ deg, const int* __restrict__ bsum,
                                  int* __restrict__ row_ptr, int* __restrict__ cursor, int n) {
    __shared__ int sd[256];
    int t = threadIdx.x;
    int base = blockIdx.x * 1024;
    int vals[4]; int s = 0;
    #pragma unroll
    for (int j = 0; j < 4; ++j) {
        int i = base + t * 4 + j;
        vals[j] = (i < n) ? deg[i] : 0;
        s += vals[j];
    }
    sd[t] = s; __syncthreads();
    for (int off = 1; off < 256; off <<= 1) {
        int tv = (t >= off) ? sd[t - off] : 0;
        __syncthreads();
        sd[t] += tv;
        __syncthreads();
    }
    int excl = sd[t] - s;
    int run = bsum[blockIdx.x] + excl;
    #pragma unroll
    for (int j = 0; j < 4; ++j) {
        int i = base + t * 4 + j;
        if (i < n) {
            cursor[i] = run;
            run += vals[j];
            row_ptr[i + 1] = run;
        }
    }
    if (blockIdx.x == 0 && t == 0) row_ptr[0] = 0;
}

__global__ void scatter_kernel(const int* __restrict__ src, const int* __restrict__ dst,
                               int* __restrict__ cursor, int* __restrict__ col, int e) {
    for (int i = blockIdx.x * blockDim.x + threadIdx.x; i < e; i += gridDim.x * blockDim.x) {
        int p = atomicAdd(&cursor[dst[i]], 1);
        col[p] = src[i];
    }
}

// ---------------- GAT aggregation (one wave per destination node) ----------
// out[d] = maybe_relu( (sum_i exp(e_i-m) * hgat[s_i]) / denom + b_gat + hlin[d] )
__global__ void gat_edge_kernel(const int* __restrict__ row_ptr, const int* __restrict__ col_src,
                                const float* __restrict__ asrc, const float* __restrict__ adst,
                                const bf16* __restrict__ hgat, const bf16* __restrict__ hlin,
                                const float* __restrict__ b_gat, int relu,
                                bf16* __restrict__ out, int ldo, int n) {
    int d = blockIdx.x * 4 + (threadIdx.x >> 6);
    int lane = threadIdx.x & 63;
    if (d >= n) return;
    float ad = adst[d];
    float e_self = leaky(asrc[d] + ad);
    int beg = row_ptr[d], end = row_ptr[d + 1];
    // pass 1: max (lane-parallel over edges)
    float mx = e_self;
    for (int i = beg + lane; i < end; i += 64) {
        int s = col_src[i];
        mx = fmaxf(mx, leaky(asrc[s] + ad));
    }
    mx = wave_max(mx);
    // pass 2: accumulate (sequential over edges, lanes parallel over features)
    float exs = __expf(e_self - mx);
    float denom = exs;
    float acc0 = exs * b2f(hgat[(long long)d * 128 + lane]);
    float acc1 = exs * b2f(hgat[(long long)d * 128 + 64 + lane]);
    for (int i = beg; i < end; ++i) {
        int s = col_src[i];
        float ex = __expf(leaky(asrc[s] + ad) - mx);
        denom += ex;
        acc0 += ex * b2f(hgat[(long long)s * 128 + lane]);
        acc1 += ex * b2f(hgat[(long long)s * 128 + 64 + lane]);
    }
    float inv = 1.0f / denom;
    float o0 = acc0 * inv + b_gat[lane] + b2f(hlin[(long long)d * 128 + lane]);
    float o1 = acc1 * inv + b_gat[64 + lane] + b2f(hlin[(long long)d * 128 + 64 + lane]);
    if (relu) { o0 = fmaxf(o0, 0.0f); o1 = fmaxf(o1, 0.0f); }
    out[(long long)d * ldo + lane] = f2b(o0);
    out[(long long)d * ldo + 64 + lane] = f2b(o1);
}

// ---------------- fill z cols 128..287: [ctrl | pert_emb | zero pad] -------
__global__ void zfill_kernel(const float* __restrict__ ctrl, const float* __restrict__ pert_table,
                             const int* __restrict__ pert, bf16* __restrict__ z, int n) {
    int wid = blockIdx.x * 4 + (threadIdx.x >> 6);
    int lane = threadIdx.x & 63;
    if (wid >= n) return;
    bf16* zr = z + (long long)wid * 288;
    const float* p = pert_table + (long long)pert[wid] * 128;
    if (lane == 0) zr[128] = f2b(ctrl[wid]);
    zr[129 + lane] = f2b(p[lane]);
    zr[193 + lane] = f2b(p[64 + lane]);
    if (lane < 31) zr[257 + lane] = (bf16)0.0f;
}

// ---------------- final: out[n] = relu(hidden[n] . Wm2 + bm2) --------------
__global__ void mlp2_kernel(const bf16* __restrict__ hidden, const float* __restrict__ Wm2,
                            const float* __restrict__ bm2, float* __restrict__ out, int n) {
    int i = blockIdx.x * blockDim.x + threadIdx.x;
    if (i >= n) return;
    float acc = bm2[0];
    const bf16x8* h8 = reinterpret_cast<const bf16x8*>(hidden + (long long)i * 64);
    #pragma unroll
    for (int jj = 0; jj < 8; ++jj) {
        bf16x8 hv = h8[jj];
        #pragma unroll
        for (int j = 0; j < 8; ++j) acc += b2f(hv[j]) * Wm2[jj * 8 + j];
    }
    out[i] = fmaxf(acc, 0.0f);
}

// ---------------------------------------------------------------------------
extern "C" void kernel_launch(void* const* d_in, const int* in_sizes, int n_in,
                              void* d_out, int out_size, void* d_ws, size_t ws_size,
                              hipStream_t stream) {
    const int N = in_sizes[0] / 64;   // 100000
    const int E = in_sizes[1] / 2;    // 1000000

    const float* x          = (const float*)d_in[0];
    const int*   ei         = (const int*)d_in[1];
    const int*   e_src      = ei;
    const int*   e_dst      = ei + E;
    const int*   pert       = (const int*)d_in[3];
    const float* ctrl       = (const float*)d_in[4];
    const int*   pos        = (const int*)d_in[5];
    const float* gene_table = (const float*)d_in[6];
    const float* pert_table = (const float*)d_in[7];
    const float* W1   = (const float*)d_in[8];
    const float* a_s1 = (const float*)d_in[9];
    const float* a_d1 = (const float*)d_in[10];
    const float* b1   = (const float*)d_in[11];
    const float* Wl1  = (const float*)d_in[12];
    const float* bl1  = (const float*)d_in[13];
    const float* W2   = (const float*)d_in[14];
    const float* a_s2 = (const float*)d_in[15];
    const float* a_d2 = (const float*)d_in[16];
    const float* b2   = (const float*)d_in[17];
    const float* Wl2  = (const float*)d_in[18];
    const float* bl2  = (const float*)d_in[19];
    const float* Wm1  = (const float*)d_in[20];
    const float* bm1  = (const float*)d_in[21];
    const float* Wm2  = (const float*)d_in[22];
    const float* bm2  = (const float*)d_in[23];

    // workspace layout
    char* ws = (char*)d_ws;
    size_t off = 0;
    auto alloc = [&](size_t bytes) {
        char* p = ws + off;
        off = (off + bytes + 255) & ~(size_t)255;
        return p;
    };
    bf16* hgat   = (bf16*)alloc((size_t)N * 128 * 2);
    bf16* hlin   = (bf16*)alloc((size_t)N * 128 * 2);
    bf16* h0     = (bf16*)alloc((size_t)N * 192 * 2);
    bf16* h1     = (bf16*)alloc((size_t)N * 128 * 2);   // contiguous after h0
    bf16* zbuf   = h0;                                   // z (N x 288) overlays h0+h1 (both dead)
    bf16* hidden = (bf16*)alloc((size_t)N * 64 * 2);
    float* asrc  = (float*)alloc((size_t)N * 4);
    float* adst  = (float*)alloc((size_t)N * 4);
    int* deg     = (int*)alloc((size_t)N * 4);
    int* cursor  = (int*)alloc((size_t)N * 4);
    int* row_ptr = (int*)alloc((size_t)(N + 1) * 4);
    int* colidx  = (int*)alloc((size_t)E * 4);
    int* bsum    = (int*)alloc((size_t)1024 * 4);
    (void)ws_size; (void)n_in; (void)out_size;

    float* out = (float*)d_out;

    const int NB = (N + 1023) / 1024;
    dim3 blk(256);
    dim3 gridWave((N + 3) / 4);
    dim3 gridGemm((N + 127) / 128);

    // --- h0 ---
    hipLaunchKernelGGL(build_h0_kernel, gridWave, blk, 0, stream, x, gene_table, pos, h0, N);
    // --- layer 1 linear parts ---
    hipLaunchKernelGGL((gemm_kernel<6, 8>), gridGemm, blk, 0, stream,
                       h0, 192, W1, 192, 128, (const float*)nullptr, 0, hgat, 128, N);
    hipLaunchKernelGGL((gemm_kernel<6, 8>), gridGemm, blk, 0, stream,
                       h0, 192, Wl1, 192, 128, bl1, 0, hlin, 128, N);
    hipLaunchKernelGGL(attn_logits_kernel, gridWave, blk, 0, stream, hgat, a_s1, a_d1, asrc, adst, N);
    // --- CSR build ---
    hipMemsetAsync(deg, 0, (size_t)N * 4, stream);
    hipLaunchKernelGGL(hist_kernel, dim3(1024), blk, 0, stream, e_dst, deg, E);
    hipLaunchKernelGGL(block_sum_kernel, dim3(NB), blk, 0, stream, deg, bsum, N);
    hipLaunchKernelGGL(scan_bsum_kernel, dim3(1), blk, 0, stream, bsum, NB);
    hipLaunchKernelGGL(scan_final_kernel, dim3(NB), blk, 0, stream, deg, bsum, row_ptr, cursor, N);
    hipLaunchKernelGGL(scatter_kernel, dim3(1024), blk, 0, stream, e_src, e_dst, cursor, colidx, E);
    // --- layer 1 aggregation -> h1 (with relu) ---
    hipLaunchKernelGGL(gat_edge_kernel, gridWave, blk, 0, stream,
                       row_ptr, colidx, asrc, adst, hgat, hlin, b1, 1, h1, 128, N);
    // --- layer 2 linear parts ---
    hipLaunchKernelGGL((gemm_kernel<4, 8>), gridGemm, blk, 0, stream,
                       h1, 128, W2, 128, 128, (const float*)nullptr, 0, hgat, 128, N);
    hipLaunchKernelGGL((gemm_kernel<4, 8>), gridGemm, blk, 0, stream,
                       h1, 128, Wl2, 128, 128, bl2, 0, hlin, 128, N);
    hipLaunchKernelGGL(attn_logits_kernel, gridWave, blk, 0, stream, hgat, a_s2, a_d2, asrc, adst, N);
    // --- layer 2 aggregation -> z[:, 0:128] (stride 288, NO relu) ---
    hipLaunchKernelGGL(gat_edge_kernel, gridWave, blk, 0, stream,
                       row_ptr, colidx, asrc, adst, hgat, hlin, b2, 0, zbuf, 288, N);
    // --- z[:, 128:288] = [ctrl | pert_emb | pad] ---
    hipLaunchKernelGGL(zfill_kernel, gridWave, blk, 0, stream, ctrl, pert_table, pert, zbuf, N);
    // --- MLP ---
    hipLaunchKernelGGL((gemm_kernel<9, 4>), gridGemm, blk, 0, stream,
                       zbuf, 288, Wm1, 257, 64, bm1, 1, hidden, 64, N);
    hipLaunchKernelGGL(mlp2_kernel, dim3((N + 255) / 256), blk, 0, stream, hidden, Wm2, bm2, out, N);
}

// Round 3
// 812.895 us; speedup vs baseline: 1.0792x; 1.0792x over previous
//
#include <hip/hip_runtime.h>
#include <hip/hip_bf16.h>

typedef __bf16 bf16;
typedef __bf16 bf16x8 __attribute__((ext_vector_type(8)));
typedef float f32x4 __attribute__((ext_vector_type(4)));

__device__ __forceinline__ float b2f(bf16 v) { return (float)v; }
__device__ __forceinline__ bf16 f2b(float v) { return (bf16)v; }

__device__ __forceinline__ float wave_sum(float v) {
    #pragma unroll
    for (int o = 32; o; o >>= 1) v += __shfl_xor(v, o);
    return v;
}
__device__ __forceinline__ float wave_max(float v) {
    #pragma unroll
    for (int o = 32; o; o >>= 1) v = fmaxf(v, __shfl_xor(v, o));
    return v;
}
__device__ __forceinline__ float leaky(float x) { return x >= 0.0f ? x : 0.2f * x; }

__device__ __forceinline__ bf16x8 zero8() {
    bf16x8 v;
    #pragma unroll
    for (int j = 0; j < 8; ++j) v[j] = (bf16)0.0f;
    return v;
}

// ---------------- h0 = [x | renorm(gene_table[pos])]  (N x 192, bf16) -------
__global__ void build_h0_kernel(const float* __restrict__ x,
                                const float* __restrict__ gene_table,
                                const int* __restrict__ pos,
                                bf16* __restrict__ h0, int n) {
    int wid = blockIdx.x * 4 + (threadIdx.x >> 6);
    int lane = threadIdx.x & 63;
    if (wid >= n) return;
    const float* g = gene_table + (long long)pos[wid] * 128;
    float p0 = g[lane], p1 = g[lane + 64];
    float ss = wave_sum(p0 * p0 + p1 * p1);
    float nrm = sqrtf(ss);
    float sc = nrm > 1.0f ? 1.0f / (nrm + 1e-7f) : 1.0f;
    bf16* o = h0 + (long long)wid * 192;
    o[lane] = f2b(x[(long long)wid * 64 + lane]);
    o[64 + lane] = f2b(p0 * sc);
    o[128 + lane] = f2b(p1 * sc);
}

// ---------------- GEMM: out = A(N x K, bf16) @ W(K x C, f32) [+bias][relu] --
// KB = ceil(K/32); A rows zero-padded to KB*32 cols. NT = C/16.
// Wave handles 32 rows (2 M-tiles), all C cols.
// Optional fused epilogues:
//   attn_s/attn_d != null : also write asrc[row]=sum(v*attn_s[col]), adst likewise
//   Wm2 != null           : hidden = relu(v+bias); out_final[row]=relu(hidden.Wm2+bm2)
template <int KB, int NT>
__global__ __launch_bounds__(256) void gemm_kernel(
    const bf16* __restrict__ A, int lda,
    const float* __restrict__ W, int Kreal, int Creal,
    const float* __restrict__ bias, int relu,
    bf16* __restrict__ out, int ldo, int nrows,
    const float* __restrict__ attn_s, const float* __restrict__ attn_d,
    float* __restrict__ asrc, float* __restrict__ adst,
    const float* __restrict__ Wm2, const float* __restrict__ bm2,
    float* __restrict__ out_final) {
    __shared__ __attribute__((aligned(16))) bf16 sW[KB * NT * 512];
    int tid = threadIdx.x;
    // stage W into LDS in B-fragment layout:
    // frag f=(kb,nt,lane): elem j = W[kb*32 + (lane>>4)*8 + j][nt*16 + (lane&15)]
    for (int f = tid; f < KB * NT * 64; f += 256) {
        int kb = f / (NT * 64);
        int rem = f % (NT * 64);
        int nt = rem / 64;
        int ln = rem % 64;
        int q = ln >> 4, m = ln & 15;
        int c = nt * 16 + m;
        #pragma unroll
        for (int j = 0; j < 8; ++j) {
            int k = kb * 32 + q * 8 + j;
            sW[f * 8 + j] = (k < Kreal) ? f2b(W[k * Creal + c]) : (bf16)0.0f;
        }
    }
    __syncthreads();

    int wave = tid >> 6, lane = tid & 63;
    int q = lane >> 4, m = lane & 15;
    long long row_base = (long long)blockIdx.x * 128 + wave * 32;

    f32x4 acc[2][NT];
    #pragma unroll
    for (int t = 0; t < 2; ++t)
        #pragma unroll
        for (int nt = 0; nt < NT; ++nt) {
            f32x4 z = {0.f, 0.f, 0.f, 0.f};
            acc[t][nt] = z;
        }

    for (int kb = 0; kb < KB; ++kb) {
        long long r0 = row_base + m;
        long long r1 = row_base + 16 + m;
        bf16x8 a0 = (r0 < nrows)
            ? *reinterpret_cast<const bf16x8*>(A + r0 * lda + kb * 32 + q * 8)
            : zero8();
        bf16x8 a1 = (r1 < nrows)
            ? *reinterpret_cast<const bf16x8*>(A + r1 * lda + kb * 32 + q * 8)
            : zero8();
        #pragma unroll
        for (int nt = 0; nt < NT; ++nt) {
            bf16x8 b = *reinterpret_cast<const bf16x8*>(&sW[((kb * NT + nt) * 64 + lane) * 8]);
            acc[0][nt] = __builtin_amdgcn_mfma_f32_16x16x32_bf16(a0, b, acc[0][nt], 0, 0, 0);
            acc[1][nt] = __builtin_amdgcn_mfma_f32_16x16x32_bf16(a1, b, acc[1][nt], 0, 0, 0);
        }
    }
    // epilogue: D[row = row_base + t*16 + q*4 + r][col = nt*16 + m]
    if (out) {
        #pragma unroll
        for (int t = 0; t < 2; ++t)
            #pragma unroll
            for (int nt = 0; nt < NT; ++nt) {
                int col = nt * 16 + m;
                float bv = bias ? bias[col] : 0.0f;
                #pragma unroll
                for (int r = 0; r < 4; ++r) {
                    long long row = row_base + t * 16 + q * 4 + r;
                    if (row < nrows) {
                        float v = acc[t][nt][r] + bv;
                        if (relu) v = fmaxf(v, 0.0f);
                        out[row * ldo + col] = f2b(v);
                    }
                }
            }
    }
    if (attn_s) {
        #pragma unroll
        for (int t = 0; t < 2; ++t)
            #pragma unroll
            for (int r = 0; r < 4; ++r) {
                float sv = 0.f, dv = 0.f;
                #pragma unroll
                for (int nt = 0; nt < NT; ++nt) {
                    float v = acc[t][nt][r];
                    int col = nt * 16 + m;
                    sv = fmaf(v, attn_s[col], sv);
                    dv = fmaf(v, attn_d[col], dv);
                }
                #pragma unroll
                for (int o = 1; o < 16; o <<= 1) {
                    sv += __shfl_xor(sv, o);
                    dv += __shfl_xor(dv, o);
                }
                long long row = row_base + t * 16 + q * 4 + r;
                if (m == 0 && row < nrows) { asrc[row] = sv; adst[row] = dv; }
            }
    }
    if (Wm2) {
        #pragma unroll
        for (int t = 0; t < 2; ++t)
            #pragma unroll
            for (int r = 0; r < 4; ++r) {
                float sv = 0.f;
                #pragma unroll
                for (int nt = 0; nt < NT; ++nt) {
                    int col = nt * 16 + m;
                    float v = fmaxf(acc[t][nt][r] + bias[col], 0.0f);
                    sv = fmaf(v, Wm2[col], sv);
                }
                #pragma unroll
                for (int o = 1; o < 16; o <<= 1) sv += __shfl_xor(sv, o);
                long long row = row_base + t * 16 + q * 4 + r;
                if (m == 0 && row < nrows) out_final[row] = fmaxf(sv + bm2[0], 0.0f);
            }
    }
}

// ---------------- CSR build ------------------------------------------------
__global__ void hist_kernel(const int* __restrict__ dst, int* __restrict__ deg, int e) {
    for (int i = blockIdx.x * blockDim.x + threadIdx.x; i < e; i += gridDim.x * blockDim.x)
        atomicAdd(&deg[dst[i]], 1);
}

__global__ void block_sum_kernel(const int* __restrict__ deg, int* __restrict__ bsum, int n) {
    __shared__ int sd[256];
    int t = threadIdx.x;
    int base = blockIdx.x * 1024;
    int s = 0;
    #pragma unroll
    for (int j = 0; j < 4; ++j) {
        int i = base + j * 256 + t;
        if (i < n) s += deg[i];
    }
    sd[t] = s; __syncthreads();
    #pragma unroll
    for (int off = 128; off; off >>= 1) {
        if (t < off) sd[t] += sd[t + off];
        __syncthreads();
    }
    if (t == 0) bsum[blockIdx.x] = sd[0];
}

__global__ void scan_bsum_kernel(int* __restrict__ bsum, int nb) {
    __shared__ int sd[256];
    int t = threadIdx.x;
    int v = (t < nb) ? bsum[t] : 0;
    sd[t] = v; __syncthreads();
    for (int off = 1; off < 256; off <<= 1) {
        int tv = (t >= off) ? sd[t - off] : 0;
        __syncthreads();
        sd[t] += tv;
        __syncthreads();
    }
    if (t < nb) bsum[t] = sd[t] - v;  // exclusive
}

__global__ void scan_final_kernel(const int* __restrict__ deg, const int* __restrict__ bsum,
                                  int* __restrict__ row_ptr, int* __restrict__ cursor, int n) {
    __shared__ int sd[256];
    int t = threadIdx.x;
    int base = blockIdx.x * 1024;
    int vals[4]; int s = 0;
    #pragma unroll
    for (int j = 0; j < 4; ++j) {
        int i = base + t * 4 + j;
        vals[j] = (i < n) ? deg[i] : 0;
        s += vals[j];
    }
    sd[t] = s; __syncthreads();
    for (int off = 1; off < 256; off <<= 1) {
        int tv = (t >= off) ? sd[t - off] : 0;
        __syncthreads();
        sd[t] += tv;
        __syncthreads();
    }
    int excl = sd[t] - s;
    int run = bsum[blockIdx.x] + excl;
    #pragma unroll
    for (int j = 0; j < 4; ++j) {
        int i = base + t * 4 + j;
        if (i < n) {
            cursor[i] = run;
            run += vals[j];
            row_ptr[i + 1] = run;
        }
    }
    if (blockIdx.x == 0 && t == 0) row_ptr[0] = 0;
}

__global__ void scatter_kernel(const int* __restrict__ src, const int* __restrict__ dst,
                               int* __restrict__ cursor, int* __restrict__ col, int e) {
    for (int i = blockIdx.x * blockDim.x + threadIdx.x; i < e; i += gridDim.x * blockDim.x) {
        int p = atomicAdd(&cursor[dst[i]], 1);
        col[p] = src[i];
    }
}

// ---------------- GAT aggregation (one wave per destination node) ----------
// out[d] = maybe_relu( (sum_i ex_i * hgat[s_i]) / denom + b_gat + hlin[d] )
// pert != null: also fill z cols 128..287 ([ctrl | pert_emb | zero pad])
__global__ void gat_edge_kernel(const int* __restrict__ row_ptr, const int* __restrict__ col_src,
                                const float* __restrict__ asrc, const float* __restrict__ adst,
                                const bf16* __restrict__ hgat, const bf16* __restrict__ hlin,
                                const float* __restrict__ b_gat, int relu,
                                float* __restrict__ exbuf,
                                bf16* __restrict__ out, int ldo, int n,
                                const float* __restrict__ ctrl,
                                const float* __restrict__ pert_table,
                                const int* __restrict__ pert) {
    int d = blockIdx.x * 4 + (threadIdx.x >> 6);
    int lane = threadIdx.x & 63;
    if (d >= n) return;
    float ad = adst[d];
    float e_self = leaky(asrc[d] + ad);
    int beg = row_ptr[d], end = row_ptr[d + 1];
    // pass 1a: logits -> exbuf, running max (lane-parallel over edges)
    float lmax = e_self;
    for (int i = beg + lane; i < end; i += 64) {
        int s = col_src[i];
        float v = leaky(asrc[s] + ad);
        exbuf[i] = v;
        lmax = fmaxf(lmax, v);
    }
    float mx = wave_max(lmax);
    // pass 1b: exp + denom (lane-parallel)
    float dsum = 0.f;
    for (int i = beg + lane; i < end; i += 64) {
        float ex = __expf(exbuf[i] - mx);
        exbuf[i] = ex;
        dsum += ex;
    }
    float exs = __expf(e_self - mx);
    float denom = wave_sum(dsum) + exs;
    // pass 2: gather-accumulate, 4-way unrolled (8 h-gathers in flight)
    float acc0 = exs * b2f(hgat[(long long)d * 128 + lane]);
    float acc1 = exs * b2f(hgat[(long long)d * 128 + 64 + lane]);
    int i = beg;
    for (; i + 4 <= end; i += 4) {
        int s0 = col_src[i], s1 = col_src[i + 1], s2 = col_src[i + 2], s3 = col_src[i + 3];
        float e0 = exbuf[i], e1 = exbuf[i + 1], e2 = exbuf[i + 2], e3 = exbuf[i + 3];
        float h00 = b2f(hgat[(long long)s0 * 128 + lane]);
        float h01 = b2f(hgat[(long long)s0 * 128 + 64 + lane]);
        float h10 = b2f(hgat[(long long)s1 * 128 + lane]);
        float h11 = b2f(hgat[(long long)s1 * 128 + 64 + lane]);
        float h20 = b2f(hgat[(long long)s2 * 128 + lane]);
        float h21 = b2f(hgat[(long long)s2 * 128 + 64 + lane]);
        float h30 = b2f(hgat[(long long)s3 * 128 + lane]);
        float h31 = b2f(hgat[(long long)s3 * 128 + 64 + lane]);
        acc0 = fmaf(e0, h00, acc0); acc1 = fmaf(e0, h01, acc1);
        acc0 = fmaf(e1, h10, acc0); acc1 = fmaf(e1, h11, acc1);
        acc0 = fmaf(e2, h20, acc0); acc1 = fmaf(e2, h21, acc1);
        acc0 = fmaf(e3, h30, acc0); acc1 = fmaf(e3, h31, acc1);
    }
    for (; i < end; ++i) {
        int s = col_src[i];
        float ex = exbuf[i];
        acc0 = fmaf(ex, b2f(hgat[(long long)s * 128 + lane]), acc0);
        acc1 = fmaf(ex, b2f(hgat[(long long)s * 128 + 64 + lane]), acc1);
    }
    float inv = 1.0f / denom;
    float o0 = acc0 * inv + b_gat[lane] + b2f(hlin[(long long)d * 128 + lane]);
    float o1 = acc1 * inv + b_gat[64 + lane] + b2f(hlin[(long long)d * 128 + 64 + lane]);
    if (relu) { o0 = fmaxf(o0, 0.0f); o1 = fmaxf(o1, 0.0f); }
    bf16* orow = out + (long long)d * ldo;
    orow[lane] = f2b(o0);
    orow[64 + lane] = f2b(o1);
    if (pert) {
        const float* p = pert_table + (long long)pert[d] * 128;
        if (lane == 0) orow[128] = f2b(ctrl[d]);
        orow[129 + lane] = f2b(p[lane]);
        orow[193 + lane] = f2b(p[64 + lane]);
        if (lane < 31) orow[257 + lane] = (bf16)0.0f;
    }
}

// ---------------------------------------------------------------------------
extern "C" void kernel_launch(void* const* d_in, const int* in_sizes, int n_in,
                              void* d_out, int out_size, void* d_ws, size_t ws_size,
                              hipStream_t stream) {
    const int N = in_sizes[0] / 64;   // 100000
    const int E = in_sizes[1] / 2;    // 1000000

    const float* x          = (const float*)d_in[0];
    const int*   ei         = (const int*)d_in[1];
    const int*   e_src      = ei;
    const int*   e_dst      = ei + E;
    const int*   pert       = (const int*)d_in[3];
    const float* ctrl       = (const float*)d_in[4];
    const int*   pos        = (const int*)d_in[5];
    const float* gene_table = (const float*)d_in[6];
    const float* pert_table = (const float*)d_in[7];
    const float* W1   = (const float*)d_in[8];
    const float* a_s1 = (const float*)d_in[9];
    const float* a_d1 = (const float*)d_in[10];
    const float* b1   = (const float*)d_in[11];
    const float* Wl1  = (const float*)d_in[12];
    const float* bl1  = (const float*)d_in[13];
    const float* W2   = (const float*)d_in[14];
    const float* a_s2 = (const float*)d_in[15];
    const float* a_d2 = (const float*)d_in[16];
    const float* b2   = (const float*)d_in[17];
    const float* Wl2  = (const float*)d_in[18];
    const float* bl2  = (const float*)d_in[19];
    const float* Wm1  = (const float*)d_in[20];
    const float* bm1  = (const float*)d_in[21];
    const float* Wm2  = (const float*)d_in[22];
    const float* bm2  = (const float*)d_in[23];

    // workspace layout
    char* ws = (char*)d_ws;
    size_t off = 0;
    auto alloc = [&](size_t bytes) {
        char* p = ws + off;
        off = (off + bytes + 255) & ~(size_t)255;
        return p;
    };
    bf16* hgat   = (bf16*)alloc((size_t)N * 128 * 2);
    bf16* hlin   = (bf16*)alloc((size_t)N * 128 * 2);
    bf16* h0     = (bf16*)alloc((size_t)N * 192 * 2);
    bf16* h1     = (bf16*)alloc((size_t)N * 128 * 2);
    bf16* zbuf   = h0;                                   // z (N x 288) overlays h0+h1 (dead)
    float* asrc  = (float*)alloc((size_t)N * 4);
    float* adst  = (float*)alloc((size_t)N * 4);
    float* exbuf = (float*)alloc((size_t)E * 4);
    int* deg     = (int*)alloc((size_t)N * 4);
    int* cursor  = (int*)alloc((size_t)N * 4);
    int* row_ptr = (int*)alloc((size_t)(N + 1) * 4);
    int* colidx  = (int*)alloc((size_t)E * 4);
    int* bsum    = (int*)alloc((size_t)1024 * 4);
    (void)ws_size; (void)n_in; (void)out_size;

    float* out = (float*)d_out;

    const int NB = (N + 1023) / 1024;
    dim3 blk(256);
    dim3 gridWave((N + 3) / 4);
    dim3 gridGemm((N + 127) / 128);

    // --- h0 ---
    hipLaunchKernelGGL(build_h0_kernel, gridWave, blk, 0, stream, x, gene_table, pos, h0, N);
    // --- layer 1 linear parts (attn logits fused into hgat gemm) ---
    hipLaunchKernelGGL((gemm_kernel<6, 8>), gridGemm, blk, 0, stream,
                       h0, 192, W1, 192, 128, (const float*)nullptr, 0, hgat, 128, N,
                       a_s1, a_d1, asrc, adst,
                       (const float*)nullptr, (const float*)nullptr, (float*)nullptr);
    hipLaunchKernelGGL((gemm_kernel<6, 8>), gridGemm, blk, 0, stream,
                       h0, 192, Wl1, 192, 128, bl1, 0, hlin, 128, N,
                       (const float*)nullptr, (const float*)nullptr, (float*)nullptr, (float*)nullptr,
                       (const float*)nullptr, (const float*)nullptr, (float*)nullptr);
    // --- CSR build ---
    hipMemsetAsync(deg, 0, (size_t)N * 4, stream);
    hipLaunchKernelGGL(hist_kernel, dim3(1024), blk, 0, stream, e_dst, deg, E);
    hipLaunchKernelGGL(block_sum_kernel, dim3(NB), blk, 0, stream, deg, bsum, N);
    hipLaunchKernelGGL(scan_bsum_kernel, dim3(1), blk, 0, stream, bsum, NB);
    hipLaunchKernelGGL(scan_final_kernel, dim3(NB), blk, 0, stream, deg, bsum, row_ptr, cursor, N);
    hipLaunchKernelGGL(scatter_kernel, dim3(1024), blk, 0, stream, e_src, e_dst, cursor, colidx, E);
    // --- layer 1 aggregation -> h1 (with relu) ---
    hipLaunchKernelGGL(gat_edge_kernel, gridWave, blk, 0, stream,
                       row_ptr, colidx, asrc, adst, hgat, hlin, b1, 1, exbuf, h1, 128, N,
                       (const float*)nullptr, (const float*)nullptr, (const int*)nullptr);
    // --- layer 2 linear parts ---
    hipLaunchKernelGGL((gemm_kernel<4, 8>), gridGemm, blk, 0, stream,
                       h1, 128, W2, 128, 128, (const float*)nullptr, 0, hgat, 128, N,
                       a_s2, a_d2, asrc, adst,
                       (const float*)nullptr, (const float*)nullptr, (float*)nullptr);
    hipLaunchKernelGGL((gemm_kernel<4, 8>), gridGemm, blk, 0, stream,
                       h1, 128, Wl2, 128, 128, bl2, 0, hlin, 128, N,
                       (const float*)nullptr, (const float*)nullptr, (float*)nullptr, (float*)nullptr,
                       (const float*)nullptr, (const float*)nullptr, (float*)nullptr);
    // --- layer 2 aggregation -> z[:, 0:128] (stride 288, NO relu) + z-fill ---
    hipLaunchKernelGGL(gat_edge_kernel, gridWave, blk, 0, stream,
                       row_ptr, colidx, asrc, adst, hgat, hlin, b2, 0, exbuf, zbuf, 288, N,
                       ctrl, pert_table, pert);
    // --- MLP (both layers fused into one gemm) ---
    hipLaunchKernelGGL((gemm_kernel<9, 4>), gridGemm, blk, 0, stream,
                       zbuf, 288, Wm1, 257, 64, bm1, 1, (bf16*)nullptr, 0, N,
                       (const float*)nullptr, (const float*)nullptr, (float*)nullptr, (float*)nullptr,
                       Wm2, bm2, out);
}

// Round 4
// 606.034 us; speedup vs baseline: 1.4476x; 1.3413x over previous
//
#include <hip/hip_runtime.h>
#include <hip/hip_bf16.h>

typedef __bf16 bf16;
typedef __bf16 bf16x8 __attribute__((ext_vector_type(8)));
typedef float f32x4 __attribute__((ext_vector_type(4)));

__device__ __forceinline__ float b2f(bf16 v) { return (float)v; }
__device__ __forceinline__ bf16 f2b(float v) { return (bf16)v; }

__device__ __forceinline__ float wave_sum(float v) {
    #pragma unroll
    for (int o = 32; o; o >>= 1) v += __shfl_xor(v, o);
    return v;
}
__device__ __forceinline__ float wave_max(float v) {
    #pragma unroll
    for (int o = 32; o; o >>= 1) v = fmaxf(v, __shfl_xor(v, o));
    return v;
}
__device__ __forceinline__ float leaky(float x) { return x >= 0.0f ? x : 0.2f * x; }

__device__ __forceinline__ bf16x8 zero8() {
    bf16x8 v;
    #pragma unroll
    for (int j = 0; j < 8; ++j) v[j] = (bf16)0.0f;
    return v;
}

// ---------------- h0 = [x | renorm(gene_table[pos])]  (N x 192, bf16) -------
__global__ void build_h0_kernel(const float* __restrict__ x,
                                const float* __restrict__ gene_table,
                                const int* __restrict__ pos,
                                bf16* __restrict__ h0, int n) {
    int wid = blockIdx.x * 4 + (threadIdx.x >> 6);
    int lane = threadIdx.x & 63;
    if (wid >= n) return;
    const float* g = gene_table + (long long)pos[wid] * 128;
    float p0 = g[lane], p1 = g[lane + 64];
    float ss = wave_sum(p0 * p0 + p1 * p1);
    float nrm = sqrtf(ss);
    float sc = nrm > 1.0f ? 1.0f / (nrm + 1e-7f) : 1.0f;
    bf16* o = h0 + (long long)wid * 192;
    o[lane] = f2b(x[(long long)wid * 64 + lane]);
    o[64 + lane] = f2b(p0 * sc);
    o[128 + lane] = f2b(p1 * sc);
}

// ---------------- weight pre-swizzle into B-fragment layout (bf16) ---------
// For matrix (KB,NT,Kreal,C): frag f=(kb,nt,ln): dst[f*8+j] =
//   W[kb*32 + (ln>>4)*8 + j][nt*16 + (ln&15)]  (0 if k >= Kreal)
__device__ __forceinline__ void swizzle_one(const float* __restrict__ W, bf16* __restrict__ dst,
                                            int f, int NT, int Kreal, int C) {
    int kb = f / (NT * 64);
    int rem = f % (NT * 64);
    int nt = rem / 64;
    int ln = rem % 64;
    int q = ln >> 4, m = ln & 15;
    int c = nt * 16 + m;
    bf16x8 v;
    #pragma unroll
    for (int j = 0; j < 8; ++j) {
        int k = kb * 32 + q * 8 + j;
        v[j] = (k < Kreal) ? f2b(W[k * C + c]) : (bf16)0.0f;
    }
    *reinterpret_cast<bf16x8*>(dst + f * 8) = v;
}

// frag counts: W1:3072  Wl1:3072  W2:2048  Wl2:2048  Wm1:2304  (total 12544)
__global__ void prep_weights_kernel(const float* __restrict__ W1, const float* __restrict__ Wl1,
                                    const float* __restrict__ W2, const float* __restrict__ Wl2,
                                    const float* __restrict__ Wm1,
                                    bf16* __restrict__ w1s, bf16* __restrict__ wl1s,
                                    bf16* __restrict__ w2s, bf16* __restrict__ wl2s,
                                    bf16* __restrict__ wm1s) {
    int g = blockIdx.x * blockDim.x + threadIdx.x;
    if (g < 3072)        swizzle_one(W1,  w1s,  g,          8, 192, 128);
    else if (g < 6144)   swizzle_one(Wl1, wl1s, g - 3072,   8, 192, 128);
    else if (g < 8192)   swizzle_one(W2,  w2s,  g - 6144,   8, 128, 128);
    else if (g < 10240)  swizzle_one(Wl2, wl2s, g - 8192,   8, 128, 128);
    else if (g < 12544)  swizzle_one(Wm1, wm1s, g - 10240,  4, 257,  64);
}

// ---------------- GEMM: out = A(N x K, bf16) @ Bsw (pre-swizzled bf16) -----
// KB = ceil(K/32); A rows zero-padded to KB*32 cols. NT = C/16.
// Wave handles 32 rows (2 M-tiles), all C cols. No LDS, no barrier.
// Optional fused epilogues:
//   attn_s/attn_d != null : asrc[row]=sum(v*attn_s[col]), adst likewise
//   Wm2 != null           : hidden = relu(v+bias); out_final[row]=relu(hidden.Wm2+bm2)
template <int KB, int NT>
__global__ __launch_bounds__(256) void gemm_kernel(
    const bf16* __restrict__ A, int lda,
    const bf16* __restrict__ Bsw,
    const float* __restrict__ bias, int relu,
    bf16* __restrict__ out, int ldo, int nrows,
    const float* __restrict__ attn_s, const float* __restrict__ attn_d,
    float* __restrict__ asrc, float* __restrict__ adst,
    const float* __restrict__ Wm2, const float* __restrict__ bm2,
    float* __restrict__ out_final) {
    int tid = threadIdx.x;
    int wave = tid >> 6, lane = tid & 63;
    int q = lane >> 4, m = lane & 15;
    long long row_base = (long long)blockIdx.x * 128 + wave * 32;

    f32x4 acc[2][NT];
    #pragma unroll
    for (int t = 0; t < 2; ++t)
        #pragma unroll
        for (int nt = 0; nt < NT; ++nt) {
            f32x4 z = {0.f, 0.f, 0.f, 0.f};
            acc[t][nt] = z;
        }

    for (int kb = 0; kb < KB; ++kb) {
        long long r0 = row_base + m;
        long long r1 = row_base + 16 + m;
        bf16x8 a0 = (r0 < nrows)
            ? *reinterpret_cast<const bf16x8*>(A + r0 * lda + kb * 32 + q * 8)
            : zero8();
        bf16x8 a1 = (r1 < nrows)
            ? *reinterpret_cast<const bf16x8*>(A + r1 * lda + kb * 32 + q * 8)
            : zero8();
        #pragma unroll
        for (int nt = 0; nt < NT; ++nt) {
            bf16x8 b = *reinterpret_cast<const bf16x8*>(Bsw + ((kb * NT + nt) * 64 + lane) * 8);
            acc[0][nt] = __builtin_amdgcn_mfma_f32_16x16x32_bf16(a0, b, acc[0][nt], 0, 0, 0);
            acc[1][nt] = __builtin_amdgcn_mfma_f32_16x16x32_bf16(a1, b, acc[1][nt], 0, 0, 0);
        }
    }
    // epilogue: D[row = row_base + t*16 + q*4 + r][col = nt*16 + m]
    if (out) {
        #pragma unroll
        for (int t = 0; t < 2; ++t)
            #pragma unroll
            for (int nt = 0; nt < NT; ++nt) {
                int col = nt * 16 + m;
                float bv = bias ? bias[col] : 0.0f;
                #pragma unroll
                for (int r = 0; r < 4; ++r) {
                    long long row = row_base + t * 16 + q * 4 + r;
                    if (row < nrows) {
                        float v = acc[t][nt][r] + bv;
                        if (relu) v = fmaxf(v, 0.0f);
                        out[row * ldo + col] = f2b(v);
                    }
                }
            }
    }
    if (attn_s) {
        #pragma unroll
        for (int t = 0; t < 2; ++t)
            #pragma unroll
            for (int r = 0; r < 4; ++r) {
                float sv = 0.f, dv = 0.f;
                #pragma unroll
                for (int nt = 0; nt < NT; ++nt) {
                    float v = acc[t][nt][r];
                    int col = nt * 16 + m;
                    sv = fmaf(v, attn_s[col], sv);
                    dv = fmaf(v, attn_d[col], dv);
                }
                #pragma unroll
                for (int o = 1; o < 16; o <<= 1) {
                    sv += __shfl_xor(sv, o);
                    dv += __shfl_xor(dv, o);
                }
                long long row = row_base + t * 16 + q * 4 + r;
                if (m == 0 && row < nrows) { asrc[row] = sv; adst[row] = dv; }
            }
    }
    if (Wm2) {
        #pragma unroll
        for (int t = 0; t < 2; ++t)
            #pragma unroll
            for (int r = 0; r < 4; ++r) {
                float sv = 0.f;
                #pragma unroll
                for (int nt = 0; nt < NT; ++nt) {
                    int col = nt * 16 + m;
                    float v = fmaxf(acc[t][nt][r] + bias[col], 0.0f);
                    sv = fmaf(v, Wm2[col], sv);
                }
                #pragma unroll
                for (int o = 1; o < 16; o <<= 1) sv += __shfl_xor(sv, o);
                long long row = row_base + t * 16 + q * 4 + r;
                if (m == 0 && row < nrows) out_final[row] = fmaxf(sv + bm2[0], 0.0f);
            }
    }
}

// ---------------- CSR build ------------------------------------------------
__global__ void hist_kernel(const int* __restrict__ dst, int* __restrict__ deg, int e) {
    for (int i = blockIdx.x * blockDim.x + threadIdx.x; i < e; i += gridDim.x * blockDim.x)
        atomicAdd(&deg[dst[i]], 1);
}

__global__ void block_sum_kernel(const int* __restrict__ deg, int* __restrict__ bsum, int n) {
    __shared__ int sd[256];
    int t = threadIdx.x;
    int base = blockIdx.x * 1024;
    int s = 0;
    #pragma unroll
    for (int j = 0; j < 4; ++j) {
        int i = base + j * 256 + t;
        if (i < n) s += deg[i];
    }
    sd[t] = s; __syncthreads();
    #pragma unroll
    for (int off = 128; off; off >>= 1) {
        if (t < off) sd[t] += sd[t + off];
        __syncthreads();
    }
    if (t == 0) bsum[blockIdx.x] = sd[0];
}

__global__ void scan_bsum_kernel(int* __restrict__ bsum, int nb) {
    __shared__ int sd[256];
    int t = threadIdx.x;
    int v = (t < nb) ? bsum[t] : 0;
    sd[t] = v; __syncthreads();
    for (int off = 1; off < 256; off <<= 1) {
        int tv = (t >= off) ? sd[t - off] : 0;
        __syncthreads();
        sd[t] += tv;
        __syncthreads();
    }
    if (t < nb) bsum[t] = sd[t] - v;  // exclusive
}

__global__ void scan_final_kernel(const int* __restrict__ deg, const int* __restrict__ bsum,
                                  int* __restrict__ row_ptr, int* __restrict__ cursor, int n) {
    __shared__ int sd[256];
    int t = threadIdx.x;
    int base = blockIdx.x * 1024;
    int vals[4]; int s = 0;
    #pragma unroll
    for (int j = 0; j < 4; ++j) {
        int i = base + t * 4 + j;
        vals[j] = (i < n) ? deg[i] : 0;
        s += vals[j];
    }
    sd[t] = s; __syncthreads();
    for (int off = 1; off < 256; off <<= 1) {
        int tv = (t >= off) ? sd[t - off] : 0;
        __syncthreads();
        sd[t] += tv;
        __syncthreads();
    }
    int excl = sd[t] - s;
    int run = bsum[blockIdx.x] + excl;
    #pragma unroll
    for (int j = 0; j < 4; ++j) {
        int i = base + t * 4 + j;
        if (i < n) {
            cursor[i] = run;
            run += vals[j];
            row_ptr[i + 1] = run;
        }
    }
    if (blockIdx.x == 0 && t == 0) row_ptr[0] = 0;
}

__global__ void scatter_kernel(const int* __restrict__ src, const int* __restrict__ dst,
                               int* __restrict__ cursor, int* __restrict__ col, int e) {
    for (int i = blockIdx.x * blockDim.x + threadIdx.x; i < e; i += gridDim.x * blockDim.x) {
        int p = atomicAdd(&cursor[dst[i]], 1);
        col[p] = src[i];
    }
}

// ---------------- GAT aggregation (one wave per destination node) ----------
// out[d] = maybe_relu( (sum_i ex_i * hgat[s_i]) / denom + b_gat + hlin[d] )
// pert != null: also fill z cols 128..287 ([ctrl | pert_emb | zero pad])
__global__ void gat_edge_kernel(const int* __restrict__ row_ptr, const int* __restrict__ col_src,
                                const float* __restrict__ asrc, const float* __restrict__ adst,
                                const bf16* __restrict__ hgat, const bf16* __restrict__ hlin,
                                const float* __restrict__ b_gat, int relu,
                                float* __restrict__ exbuf,
                                bf16* __restrict__ out, int ldo, int n,
                                const float* __restrict__ ctrl,
                                const float* __restrict__ pert_table,
                                const int* __restrict__ pert) {
    int d = blockIdx.x * 4 + (threadIdx.x >> 6);
    int lane = threadIdx.x & 63;
    if (d >= n) return;
    float ad = adst[d];
    float e_self = leaky(asrc[d] + ad);
    int beg = row_ptr[d], end = row_ptr[d + 1];
    // pass 1a: logits -> exbuf, running max (lane-parallel over edges)
    float lmax = e_self;
    for (int i = beg + lane; i < end; i += 64) {
        int s = col_src[i];
        float v = leaky(asrc[s] + ad);
        exbuf[i] = v;
        lmax = fmaxf(lmax, v);
    }
    float mx = wave_max(lmax);
    // pass 1b: exp + denom (lane-parallel)
    float dsum = 0.f;
    for (int i = beg + lane; i < end; i += 64) {
        float ex = __expf(exbuf[i] - mx);
        exbuf[i] = ex;
        dsum += ex;
    }
    float exs = __expf(e_self - mx);
    float denom = wave_sum(dsum) + exs;
    // pass 2: gather-accumulate, 4-way unrolled (8 h-gathers in flight)
    float acc0 = exs * b2f(hgat[(long long)d * 128 + lane]);
    float acc1 = exs * b2f(hgat[(long long)d * 128 + 64 + lane]);
    int i = beg;
    for (; i + 4 <= end; i += 4) {
        int s0 = col_src[i], s1 = col_src[i + 1], s2 = col_src[i + 2], s3 = col_src[i + 3];
        float e0 = exbuf[i], e1 = exbuf[i + 1], e2 = exbuf[i + 2], e3 = exbuf[i + 3];
        float h00 = b2f(hgat[(long long)s0 * 128 + lane]);
        float h01 = b2f(hgat[(long long)s0 * 128 + 64 + lane]);
        float h10 = b2f(hgat[(long long)s1 * 128 + lane]);
        float h11 = b2f(hgat[(long long)s1 * 128 + 64 + lane]);
        float h20 = b2f(hgat[(long long)s2 * 128 + lane]);
        float h21 = b2f(hgat[(long long)s2 * 128 + 64 + lane]);
        float h30 = b2f(hgat[(long long)s3 * 128 + lane]);
        float h31 = b2f(hgat[(long long)s3 * 128 + 64 + lane]);
        acc0 = fmaf(e0, h00, acc0); acc1 = fmaf(e0, h01, acc1);
        acc0 = fmaf(e1, h10, acc0); acc1 = fmaf(e1, h11, acc1);
        acc0 = fmaf(e2, h20, acc0); acc1 = fmaf(e2, h21, acc1);
        acc0 = fmaf(e3, h30, acc0); acc1 = fmaf(e3, h31, acc1);
    }
    for (; i < end; ++i) {
        int s = col_src[i];
        float ex = exbuf[i];
        acc0 = fmaf(ex, b2f(hgat[(long long)s * 128 + lane]), acc0);
        acc1 = fmaf(ex, b2f(hgat[(long long)s * 128 + 64 + lane]), acc1);
    }
    float inv = 1.0f / denom;
    float o0 = acc0 * inv + b_gat[lane] + b2f(hlin[(long long)d * 128 + lane]);
    float o1 = acc1 * inv + b_gat[64 + lane] + b2f(hlin[(long long)d * 128 + 64 + lane]);
    if (relu) { o0 = fmaxf(o0, 0.0f); o1 = fmaxf(o1, 0.0f); }
    bf16* orow = out + (long long)d * ldo;
    orow[lane] = f2b(o0);
    orow[64 + lane] = f2b(o1);
    if (pert) {
        const float* p = pert_table + (long long)pert[d] * 128;
        if (lane == 0) orow[128] = f2b(ctrl[d]);
        orow[129 + lane] = f2b(p[lane]);
        orow[193 + lane] = f2b(p[64 + lane]);
        if (lane < 31) orow[257 + lane] = (bf16)0.0f;
    }
}

// ---------------------------------------------------------------------------
extern "C" void kernel_launch(void* const* d_in, const int* in_sizes, int n_in,
                              void* d_out, int out_size, void* d_ws, size_t ws_size,
                              hipStream_t stream) {
    const int N = in_sizes[0] / 64;   // 100000
    const int E = in_sizes[1] / 2;    // 1000000

    const float* x          = (const float*)d_in[0];
    const int*   ei         = (const int*)d_in[1];
    const int*   e_src      = ei;
    const int*   e_dst      = ei + E;
    const int*   pert       = (const int*)d_in[3];
    const float* ctrl       = (const float*)d_in[4];
    const int*   pos        = (const int*)d_in[5];
    const float* gene_table = (const float*)d_in[6];
    const float* pert_table = (const float*)d_in[7];
    const float* W1   = (const float*)d_in[8];
    const float* a_s1 = (const float*)d_in[9];
    const float* a_d1 = (const float*)d_in[10];
    const float* b1   = (const float*)d_in[11];
    const float* Wl1  = (const float*)d_in[12];
    const float* bl1  = (const float*)d_in[13];
    const float* W2   = (const float*)d_in[14];
    const float* a_s2 = (const float*)d_in[15];
    const float* a_d2 = (const float*)d_in[16];
    const float* b2   = (const float*)d_in[17];
    const float* Wl2  = (const float*)d_in[18];
    const float* bl2  = (const float*)d_in[19];
    const float* Wm1  = (const float*)d_in[20];
    const float* bm1  = (const float*)d_in[21];
    const float* Wm2  = (const float*)d_in[22];
    const float* bm2  = (const float*)d_in[23];

    // workspace layout
    char* ws = (char*)d_ws;
    size_t off = 0;
    auto alloc = [&](size_t bytes) {
        char* p = ws + off;
        off = (off + bytes + 255) & ~(size_t)255;
        return p;
    };
    bf16* hgat   = (bf16*)alloc((size_t)N * 128 * 2);
    bf16* hlin   = (bf16*)alloc((size_t)N * 128 * 2);
    bf16* h0     = (bf16*)alloc((size_t)N * 192 * 2);
    bf16* h1     = (bf16*)alloc((size_t)N * 128 * 2);
    bf16* zbuf   = h0;                                   // z (N x 288) overlays h0+h1 (dead)
    float* asrc  = (float*)alloc((size_t)N * 4);
    float* adst  = (float*)alloc((size_t)N * 4);
    float* exbuf = (float*)alloc((size_t)E * 4);
    int* deg     = (int*)alloc((size_t)N * 4);
    int* cursor  = (int*)alloc((size_t)N * 4);
    int* row_ptr = (int*)alloc((size_t)(N + 1) * 4);
    int* colidx  = (int*)alloc((size_t)E * 4);
    int* bsum    = (int*)alloc((size_t)1024 * 4);
    bf16* w1s    = (bf16*)alloc((size_t)3072 * 8 * 2);
    bf16* wl1s   = (bf16*)alloc((size_t)3072 * 8 * 2);
    bf16* w2s    = (bf16*)alloc((size_t)2048 * 8 * 2);
    bf16* wl2s   = (bf16*)alloc((size_t)2048 * 8 * 2);
    bf16* wm1s   = (bf16*)alloc((size_t)2304 * 8 * 2);
    (void)ws_size; (void)n_in; (void)out_size;

    float* out = (float*)d_out;

    const int NB = (N + 1023) / 1024;
    dim3 blk(256);
    dim3 gridWave((N + 3) / 4);
    dim3 gridGemm((N + 127) / 128);

    // --- weight pre-swizzle (12544 fragment-groups) ---
    hipLaunchKernelGGL(prep_weights_kernel, dim3(49), blk, 0, stream,
                       W1, Wl1, W2, Wl2, Wm1, w1s, wl1s, w2s, wl2s, wm1s);
    // --- h0 ---
    hipLaunchKernelGGL(build_h0_kernel, gridWave, blk, 0, stream, x, gene_table, pos, h0, N);
    // --- layer 1 linear parts (attn logits fused into hgat gemm) ---
    hipLaunchKernelGGL((gemm_kernel<6, 8>), gridGemm, blk, 0, stream,
                       h0, 192, w1s, (const float*)nullptr, 0, hgat, 128, N,
                       a_s1, a_d1, asrc, adst,
                       (const float*)nullptr, (const float*)nullptr, (float*)nullptr);
    hipLaunchKernelGGL((gemm_kernel<6, 8>), gridGemm, blk, 0, stream,
                       h0, 192, wl1s, bl1, 0, hlin, 128, N,
                       (const float*)nullptr, (const float*)nullptr, (float*)nullptr, (float*)nullptr,
                       (const float*)nullptr, (const float*)nullptr, (float*)nullptr);
    // --- CSR build ---
    hipMemsetAsync(deg, 0, (size_t)N * 4, stream);
    hipLaunchKernelGGL(hist_kernel, dim3(1024), blk, 0, stream, e_dst, deg, E);
    hipLaunchKernelGGL(block_sum_kernel, dim3(NB), blk, 0, stream, deg, bsum, N);
    hipLaunchKernelGGL(scan_bsum_kernel, dim3(1), blk, 0, stream, bsum, NB);
    hipLaunchKernelGGL(scan_final_kernel, dim3(NB), blk, 0, stream, deg, bsum, row_ptr, cursor, N);
    hipLaunchKernelGGL(scatter_kernel, dim3(1024), blk, 0, stream, e_src, e_dst, cursor, colidx, E);
    // --- layer 1 aggregation -> h1 (with relu) ---
    hipLaunchKernelGGL(gat_edge_kernel, gridWave, blk, 0, stream,
                       row_ptr, colidx, asrc, adst, hgat, hlin, b1, 1, exbuf, h1, 128, N,
                       (const float*)nullptr, (const float*)nullptr, (const int*)nullptr);
    // --- layer 2 linear parts ---
    hipLaunchKernelGGL((gemm_kernel<4, 8>), gridGemm, blk, 0, stream,
                       h1, 128, w2s, (const float*)nullptr, 0, hgat, 128, N,
                       a_s2, a_d2, asrc, adst,
                       (const float*)nullptr, (const float*)nullptr, (float*)nullptr);
    hipLaunchKernelGGL((gemm_kernel<4, 8>), gridGemm, blk, 0, stream,
                       h1, 128, wl2s, bl2, 0, hlin, 128, N,
                       (const float*)nullptr, (const float*)nullptr, (float*)nullptr, (float*)nullptr,
                       (const float*)nullptr, (const float*)nullptr, (float*)nullptr);
    // --- layer 2 aggregation -> z[:, 0:128] (stride 288, NO relu) + z-fill ---
    hipLaunchKernelGGL(gat_edge_kernel, gridWave, blk, 0, stream,
                       row_ptr, colidx, asrc, adst, hgat, hlin, b2, 0, exbuf, zbuf, 288, N,
                       ctrl, pert_table, pert);
    // --- MLP (both layers fused into one gemm) ---
    hipLaunchKernelGGL((gemm_kernel<9, 4>), gridGemm, blk, 0, stream,
                       zbuf, 288, wm1s, bm1, 1, (bf16*)nullptr, 0, N,
                       (const float*)nullptr, (const float*)nullptr, (float*)nullptr, (float*)nullptr,
                       Wm2, bm2, out);
}

// Round 5
// 556.343 us; speedup vs baseline: 1.5769x; 1.0893x over previous
//
#include <hip/hip_runtime.h>
#include <hip/hip_bf16.h>

typedef __bf16 bf16;
typedef __bf16 bf16x8 __attribute__((ext_vector_type(8)));
typedef __bf16 bf16x4 __attribute__((ext_vector_type(4)));
typedef __bf16 bf16x2 __attribute__((ext_vector_type(2)));
typedef float f32x4 __attribute__((ext_vector_type(4)));

__device__ __forceinline__ float b2f(bf16 v) { return (float)v; }
__device__ __forceinline__ bf16 f2b(float v) { return (bf16)v; }

__device__ __forceinline__ float wave_sum(float v) {
    #pragma unroll
    for (int o = 32; o; o >>= 1) v += __shfl_xor(v, o);
    return v;
}
__device__ __forceinline__ float leaky(float x) { return x >= 0.0f ? x : 0.2f * x; }

__device__ __forceinline__ bf16x8 zero8() {
    bf16x8 v;
    #pragma unroll
    for (int j = 0; j < 8; ++j) v[j] = (bf16)0.0f;
    return v;
}

// ---------------- h0 = [x | renorm(gene_table[pos])]  (N x 192, bf16) -------
__global__ void build_h0_kernel(const float* __restrict__ x,
                                const float* __restrict__ gene_table,
                                const int* __restrict__ pos,
                                bf16* __restrict__ h0, int n) {
    int wid = blockIdx.x * 4 + (threadIdx.x >> 6);
    int lane = threadIdx.x & 63;
    if (wid >= n) return;
    const float* g = gene_table + (long long)pos[wid] * 128;
    float p0 = g[lane], p1 = g[lane + 64];
    float ss = wave_sum(p0 * p0 + p1 * p1);
    float nrm = sqrtf(ss);
    float sc = nrm > 1.0f ? 1.0f / (nrm + 1e-7f) : 1.0f;
    bf16* o = h0 + (long long)wid * 192;
    o[lane] = f2b(x[(long long)wid * 64 + lane]);
    o[64 + lane] = f2b(p0 * sc);
    o[128 + lane] = f2b(p1 * sc);
}

// ---------------- weight pre-swizzle into MFMA fragment layout (bf16) ------
// frag f=(kb,nt,ln): dst[f*8+j] = W[kb*32 + (ln>>4)*8 + j][nt*16 + (ln&15)]
// (serves as A-operand layout: 16-index = w-col, k = q*8+j)
__device__ __forceinline__ void swizzle_one(const float* __restrict__ W, bf16* __restrict__ dst,
                                            int f, int NT, int Kreal, int C) {
    int kb = f / (NT * 64);
    int rem = f % (NT * 64);
    int nt = rem / 64;
    int ln = rem % 64;
    int q = ln >> 4, m = ln & 15;
    int c = nt * 16 + m;
    bf16x8 v;
    #pragma unroll
    for (int j = 0; j < 8; ++j) {
        int k = kb * 32 + q * 8 + j;
        v[j] = (k < Kreal) ? f2b(W[k * C + c]) : (bf16)0.0f;
    }
    *reinterpret_cast<bf16x8*>(dst + f * 8) = v;
}

// frag counts: W1:3072  Wl1:3072  W2:2048  Wl2:2048  Wm1:2304  (total 12544)
__global__ void prep_weights_kernel(const float* __restrict__ W1, const float* __restrict__ Wl1,
                                    const float* __restrict__ W2, const float* __restrict__ Wl2,
                                    const float* __restrict__ Wm1,
                                    bf16* __restrict__ w1s, bf16* __restrict__ wl1s,
                                    bf16* __restrict__ w2s, bf16* __restrict__ wl2s,
                                    bf16* __restrict__ wm1s) {
    int g = blockIdx.x * blockDim.x + threadIdx.x;
    if (g < 3072)        swizzle_one(W1,  w1s,  g,          8, 192, 128);
    else if (g < 6144)   swizzle_one(Wl1, wl1s, g - 3072,   8, 192, 128);
    else if (g < 8192)   swizzle_one(W2,  w2s,  g - 6144,   8, 128, 128);
    else if (g < 10240)  swizzle_one(Wl2, wl2s, g - 8192,   8, 128, 128);
    else if (g < 12544)  swizzle_one(Wm1, wm1s, g - 10240,  4, 257,  64);
}

// ---------------- GEMM: out = A(N x K, bf16) @ W (pre-swizzled bf16) -------
// Operand-swapped MFMA: W is the A-operand (M = out cols), activation rows are
// the B-operand (N = out rows). D: out_row = lane&15 (+16t), out_col =
// nt*16 + q*4 + r  -> per-lane 4 consecutive cols => 8 B vector stores.
// KB = ceil(K/32); NT = C/16. Wave handles 32 rows, all C cols. No LDS.
template <int KB, int NT>
__global__ __launch_bounds__(256) void gemm_kernel(
    const bf16* __restrict__ A, int lda,
    const bf16* __restrict__ Wsw,
    const float* __restrict__ bias, int relu,
    bf16* __restrict__ out, int ldo, int nrows,
    const float* __restrict__ attn_s, const float* __restrict__ attn_d,
    float* __restrict__ asrc, float* __restrict__ adst,
    const float* __restrict__ Wm2, const float* __restrict__ bm2,
    float* __restrict__ out_final) {
    int tid = threadIdx.x;
    int wave = tid >> 6, lane = tid & 63;
    int q = lane >> 4, m = lane & 15;
    long long row_base = (long long)blockIdx.x * 128 + wave * 32;
    long long r0 = row_base + m;        // t=0 row for this lane's B-frag
    long long r1 = row_base + 16 + m;   // t=1 row
    bool v0 = r0 < nrows, v1 = r1 < nrows;

    f32x4 acc[2][NT];
    #pragma unroll
    for (int t = 0; t < 2; ++t)
        #pragma unroll
        for (int nt = 0; nt < NT; ++nt) {
            f32x4 z = {0.f, 0.f, 0.f, 0.f};
            acc[t][nt] = z;
        }

    bf16x8 b0 = v0 ? *reinterpret_cast<const bf16x8*>(A + r0 * lda + q * 8) : zero8();
    bf16x8 b1 = v1 ? *reinterpret_cast<const bf16x8*>(A + r1 * lda + q * 8) : zero8();
    #pragma unroll
    for (int kb = 0; kb < KB; ++kb) {
        bf16x8 nb0, nb1;
        if (kb + 1 < KB) {
            nb0 = v0 ? *reinterpret_cast<const bf16x8*>(A + r0 * lda + (kb + 1) * 32 + q * 8) : zero8();
            nb1 = v1 ? *reinterpret_cast<const bf16x8*>(A + r1 * lda + (kb + 1) * 32 + q * 8) : zero8();
        }
        #pragma unroll
        for (int nt = 0; nt < NT; ++nt) {
            bf16x8 w = *reinterpret_cast<const bf16x8*>(Wsw + ((kb * NT + nt) * 64 + lane) * 8);
            acc[0][nt] = __builtin_amdgcn_mfma_f32_16x16x32_bf16(w, b0, acc[0][nt], 0, 0, 0);
            acc[1][nt] = __builtin_amdgcn_mfma_f32_16x16x32_bf16(w, b1, acc[1][nt], 0, 0, 0);
        }
        b0 = nb0; b1 = nb1;
    }
    // epilogue: row = row_base + t*16 + m; cols = nt*16 + q*4 + r (r=0..3)
    if (out) {
        #pragma unroll
        for (int t = 0; t < 2; ++t) {
            long long row = t ? r1 : r0;
            if (row < nrows) {
                #pragma unroll
                for (int nt = 0; nt < NT; ++nt) {
                    int c0 = nt * 16 + q * 4;
                    bf16x4 ov;
                    #pragma unroll
                    for (int r = 0; r < 4; ++r) {
                        float v = acc[t][nt][r] + (bias ? bias[c0 + r] : 0.0f);
                        if (relu) v = fmaxf(v, 0.0f);
                        ov[r] = f2b(v);
                    }
                    *reinterpret_cast<bf16x4*>(out + row * ldo + c0) = ov;
                }
            }
        }
    }
    if (attn_s) {
        #pragma unroll
        for (int t = 0; t < 2; ++t) {
            float sv = 0.f, dv = 0.f;
            #pragma unroll
            for (int nt = 0; nt < NT; ++nt) {
                int c0 = nt * 16 + q * 4;
                #pragma unroll
                for (int r = 0; r < 4; ++r) {
                    float v = acc[t][nt][r];
                    sv = fmaf(v, attn_s[c0 + r], sv);
                    dv = fmaf(v, attn_d[c0 + r], dv);
                }
            }
            sv += __shfl_xor(sv, 16); sv += __shfl_xor(sv, 32);
            dv += __shfl_xor(dv, 16); dv += __shfl_xor(dv, 32);
            long long row = t ? r1 : r0;
            if (q == 0 && row < nrows) { asrc[row] = sv; adst[row] = dv; }
        }
    }
    if (Wm2) {
        #pragma unroll
        for (int t = 0; t < 2; ++t) {
            float sv = 0.f;
            #pragma unroll
            for (int nt = 0; nt < NT; ++nt) {
                int c0 = nt * 16 + q * 4;
                #pragma unroll
                for (int r = 0; r < 4; ++r) {
                    float v = fmaxf(acc[t][nt][r] + bias[c0 + r], 0.0f);
                    sv = fmaf(v, Wm2[c0 + r], sv);
                }
            }
            sv += __shfl_xor(sv, 16); sv += __shfl_xor(sv, 32);
            long long row = t ? r1 : r0;
            if (q == 0 && row < nrows) out_final[row] = fmaxf(sv + bm2[0], 0.0f);
        }
    }
}

// ---------------- CSR build ------------------------------------------------
__global__ void hist_kernel(const int* __restrict__ dst, int* __restrict__ deg, int e) {
    for (int i = blockIdx.x * blockDim.x + threadIdx.x; i < e; i += gridDim.x * blockDim.x)
        atomicAdd(&deg[dst[i]], 1);
}

__global__ void block_sum_kernel(const int* __restrict__ deg, int* __restrict__ bsum, int n) {
    __shared__ int sd[256];
    int t = threadIdx.x;
    int base = blockIdx.x * 1024;
    int s = 0;
    #pragma unroll
    for (int j = 0; j < 4; ++j) {
        int i = base + j * 256 + t;
        if (i < n) s += deg[i];
    }
    sd[t] = s; __syncthreads();
    #pragma unroll
    for (int off = 128; off; off >>= 1) {
        if (t < off) sd[t] += sd[t + off];
        __syncthreads();
    }
    if (t == 0) bsum[blockIdx.x] = sd[0];
}

__global__ void scan_bsum_kernel(int* __restrict__ bsum, int nb) {
    __shared__ int sd[256];
    int t = threadIdx.x;
    int v = (t < nb) ? bsum[t] : 0;
    sd[t] = v; __syncthreads();
    for (int off = 1; off < 256; off <<= 1) {
        int tv = (t >= off) ? sd[t - off] : 0;
        __syncthreads();
        sd[t] += tv;
        __syncthreads();
    }
    if (t < nb) bsum[t] = sd[t] - v;  // exclusive
}

__global__ void scan_final_kernel(const int* __restrict__ deg, const int* __restrict__ bsum,
                                  int* __restrict__ row_ptr, int* __restrict__ cursor, int n) {
    __shared__ int sd[256];
    int t = threadIdx.x;
    int base = blockIdx.x * 1024;
    int vals[4]; int s = 0;
    #pragma unroll
    for (int j = 0; j < 4; ++j) {
        int i = base + t * 4 + j;
        vals[j] = (i < n) ? deg[i] : 0;
        s += vals[j];
    }
    sd[t] = s; __syncthreads();
    for (int off = 1; off < 256; off <<= 1) {
        int tv = (t >= off) ? sd[t - off] : 0;
        __syncthreads();
        sd[t] += tv;
        __syncthreads();
    }
    int excl = sd[t] - s;
    int run = bsum[blockIdx.x] + excl;
    #pragma unroll
    for (int j = 0; j < 4; ++j) {
        int i = base + t * 4 + j;
        if (i < n) {
            cursor[i] = run;
            run += vals[j];
            row_ptr[i + 1] = run;
        }
    }
    if (blockIdx.x == 0 && t == 0) row_ptr[0] = 0;
}

__global__ void scatter_kernel(const int* __restrict__ src, const int* __restrict__ dst,
                               int* __restrict__ cursor, int* __restrict__ col, int e) {
    for (int i = blockIdx.x * blockDim.x + threadIdx.x; i < e; i += gridDim.x * blockDim.x) {
        int p = atomicAdd(&cursor[dst[i]], 1);
        col[p] = src[i];
    }
}

// ---------------- GAT aggregation: single-pass online softmax --------------
// One wave per destination node; lane holds features 2*lane, 2*lane+1.
// out[d] = maybe_relu( (sum_i ex_i * hgat[s_i]) / denom + b_gat + hlin[d] )
// pert != null: also fill z cols 128..287 ([ctrl | pert_emb | zero pad])
__global__ void gat_edge_kernel(const int* __restrict__ row_ptr, const int* __restrict__ col_src,
                                const float* __restrict__ asrc, const float* __restrict__ adst,
                                const bf16* __restrict__ hgat, const bf16* __restrict__ hlin,
                                const float* __restrict__ b_gat, int relu,
                                bf16* __restrict__ out, int ldo, int n,
                                const float* __restrict__ ctrl,
                                const float* __restrict__ pert_table,
                                const int* __restrict__ pert) {
    int d = blockIdx.x * 4 + (threadIdx.x >> 6);
    int lane = threadIdx.x & 63;
    if (d >= n) return;
    float ad = adst[d];
    float mx = leaky(asrc[d] + ad);   // e_self; running max
    bf16x2 hd = *reinterpret_cast<const bf16x2*>(hgat + (long long)d * 128 + 2 * lane);
    float acc0 = b2f(hd[0]), acc1 = b2f(hd[1]);  // self weight exp(0)=1
    float den = 1.0f;
    int beg = row_ptr[d], end = row_ptr[d + 1];
    int i = beg;
    for (; i + 8 <= end; i += 8) {
        int s[8];
        #pragma unroll
        for (int j = 0; j < 8; ++j) s[j] = col_src[i + j];
        bf16x2 h[8];
        #pragma unroll
        for (int j = 0; j < 8; ++j)
            h[j] = *reinterpret_cast<const bf16x2*>(hgat + (long long)s[j] * 128 + 2 * lane);
        float e[8];
        #pragma unroll
        for (int j = 0; j < 8; ++j) e[j] = leaky(asrc[s[j]] + ad);
        float bm = e[0];
        #pragma unroll
        for (int j = 1; j < 8; ++j) bm = fmaxf(bm, e[j]);
        float newm = fmaxf(mx, bm);
        float sc = __expf(mx - newm);
        acc0 *= sc; acc1 *= sc; den *= sc;
        #pragma unroll
        for (int j = 0; j < 8; ++j) {
            float w = __expf(e[j] - newm);
            den += w;
            acc0 = fmaf(w, b2f(h[j][0]), acc0);
            acc1 = fmaf(w, b2f(h[j][1]), acc1);
        }
        mx = newm;
    }
    for (; i < end; ++i) {
        int s = col_src[i];
        float e = leaky(asrc[s] + ad);
        bf16x2 h = *reinterpret_cast<const bf16x2*>(hgat + (long long)s * 128 + 2 * lane);
        float newm = fmaxf(mx, e);
        float sc = __expf(mx - newm);
        float w = __expf(e - newm);
        acc0 = fmaf(w, b2f(h[0]), acc0 * sc);
        acc1 = fmaf(w, b2f(h[1]), acc1 * sc);
        den = den * sc + w;
        mx = newm;
    }
    float inv = 1.0f / den;
    bf16x2 hl = *reinterpret_cast<const bf16x2*>(hlin + (long long)d * 128 + 2 * lane);
    float bg0 = b_gat[2 * lane], bg1 = b_gat[2 * lane + 1];
    float o0 = acc0 * inv + bg0 + b2f(hl[0]);
    float o1 = acc1 * inv + bg1 + b2f(hl[1]);
    if (relu) { o0 = fmaxf(o0, 0.0f); o1 = fmaxf(o1, 0.0f); }
    bf16* orow = out + (long long)d * ldo;
    bf16x2 ov; ov[0] = f2b(o0); ov[1] = f2b(o1);
    *reinterpret_cast<bf16x2*>(orow + 2 * lane) = ov;
    if (pert) {
        const float* p = pert_table + (long long)pert[d] * 128;
        if (lane == 0) orow[128] = f2b(ctrl[d]);
        orow[129 + lane] = f2b(p[lane]);
        orow[193 + lane] = f2b(p[64 + lane]);
        if (lane < 31) orow[257 + lane] = (bf16)0.0f;
    }
}

// ---------------------------------------------------------------------------
extern "C" void kernel_launch(void* const* d_in, const int* in_sizes, int n_in,
                              void* d_out, int out_size, void* d_ws, size_t ws_size,
                              hipStream_t stream) {
    const int N = in_sizes[0] / 64;   // 100000
    const int E = in_sizes[1] / 2;    // 1000000

    const float* x          = (const float*)d_in[0];
    const int*   ei         = (const int*)d_in[1];
    const int*   e_src      = ei;
    const int*   e_dst      = ei + E;
    const int*   pert       = (const int*)d_in[3];
    const float* ctrl       = (const float*)d_in[4];
    const int*   pos        = (const int*)d_in[5];
    const float* gene_table = (const float*)d_in[6];
    const float* pert_table = (const float*)d_in[7];
    const float* W1   = (const float*)d_in[8];
    const float* a_s1 = (const float*)d_in[9];
    const float* a_d1 = (const float*)d_in[10];
    const float* b1   = (const float*)d_in[11];
    const float* Wl1  = (const float*)d_in[12];
    const float* bl1  = (const float*)d_in[13];
    const float* W2   = (const float*)d_in[14];
    const float* a_s2 = (const float*)d_in[15];
    const float* a_d2 = (const float*)d_in[16];
    const float* b2   = (const float*)d_in[17];
    const float* Wl2  = (const float*)d_in[18];
    const float* bl2  = (const float*)d_in[19];
    const float* Wm1  = (const float*)d_in[20];
    const float* bm1  = (const float*)d_in[21];
    const float* Wm2  = (const float*)d_in[22];
    const float* bm2  = (const float*)d_in[23];

    // workspace layout
    char* ws = (char*)d_ws;
    size_t off = 0;
    auto alloc = [&](size_t bytes) {
        char* p = ws + off;
        off = (off + bytes + 255) & ~(size_t)255;
        return p;
    };
    bf16* hgat   = (bf16*)alloc((size_t)N * 128 * 2);
    bf16* hlin   = (bf16*)alloc((size_t)N * 128 * 2);
    bf16* h0     = (bf16*)alloc((size_t)N * 192 * 2);
    bf16* h1     = (bf16*)alloc((size_t)N * 128 * 2);
    bf16* zbuf   = h0;                                   // z (N x 288) overlays h0+h1 (dead)
    float* asrc  = (float*)alloc((size_t)N * 4);
    float* adst  = (float*)alloc((size_t)N * 4);
    int* deg     = (int*)alloc((size_t)N * 4);
    int* cursor  = (int*)alloc((size_t)N * 4);
    int* row_ptr = (int*)alloc((size_t)(N + 1) * 4);
    int* colidx  = (int*)alloc((size_t)E * 4);
    int* bsum    = (int*)alloc((size_t)1024 * 4);
    bf16* w1s    = (bf16*)alloc((size_t)3072 * 8 * 2);
    bf16* wl1s   = (bf16*)alloc((size_t)3072 * 8 * 2);
    bf16* w2s    = (bf16*)alloc((size_t)2048 * 8 * 2);
    bf16* wl2s   = (bf16*)alloc((size_t)2048 * 8 * 2);
    bf16* wm1s   = (bf16*)alloc((size_t)2304 * 8 * 2);
    (void)ws_size; (void)n_in; (void)out_size;

    float* out = (float*)d_out;

    const int NB = (N + 1023) / 1024;
    dim3 blk(256);
    dim3 gridWave((N + 3) / 4);
    dim3 gridGemm((N + 127) / 128);

    // --- weight pre-swizzle (12544 fragment-groups) ---
    hipLaunchKernelGGL(prep_weights_kernel, dim3(49), blk, 0, stream,
                       W1, Wl1, W2, Wl2, Wm1, w1s, wl1s, w2s, wl2s, wm1s);
    // --- h0 ---
    hipLaunchKernelGGL(build_h0_kernel, gridWave, blk, 0, stream, x, gene_table, pos, h0, N);
    // --- layer 1 linear parts (attn logits fused into hgat gemm) ---
    hipLaunchKernelGGL((gemm_kernel<6, 8>), gridGemm, blk, 0, stream,
                       h0, 192, w1s, (const float*)nullptr, 0, hgat, 128, N,
                       a_s1, a_d1, asrc, adst,
                       (const float*)nullptr, (const float*)nullptr, (float*)nullptr);
    hipLaunchKernelGGL((gemm_kernel<6, 8>), gridGemm, blk, 0, stream,
                       h0, 192, wl1s, bl1, 0, hlin, 128, N,
                       (const float*)nullptr, (const float*)nullptr, (float*)nullptr, (float*)nullptr,
                       (const float*)nullptr, (const float*)nullptr, (float*)nullptr);
    // --- CSR build ---
    hipMemsetAsync(deg, 0, (size_t)N * 4, stream);
    hipLaunchKernelGGL(hist_kernel, dim3(1024), blk, 0, stream, e_dst, deg, E);
    hipLaunchKernelGGL(block_sum_kernel, dim3(NB), blk, 0, stream, deg, bsum, N);
    hipLaunchKernelGGL(scan_bsum_kernel, dim3(1), blk, 0, stream, bsum, NB);
    hipLaunchKernelGGL(scan_final_kernel, dim3(NB), blk, 0, stream, deg, bsum, row_ptr, cursor, N);
    hipLaunchKernelGGL(scatter_kernel, dim3(1024), blk, 0, stream, e_src, e_dst, cursor, colidx, E);
    // --- layer 1 aggregation -> h1 (with relu) ---
    hipLaunchKernelGGL(gat_edge_kernel, gridWave, blk, 0, stream,
                       row_ptr, colidx, asrc, adst, hgat, hlin, b1, 1, h1, 128, N,
                       (const float*)nullptr, (const float*)nullptr, (const int*)nullptr);
    // --- layer 2 linear parts ---
    hipLaunchKernelGGL((gemm_kernel<4, 8>), gridGemm, blk, 0, stream,
                       h1, 128, w2s, (const float*)nullptr, 0, hgat, 128, N,
                       a_s2, a_d2, asrc, adst,
                       (const float*)nullptr, (const float*)nullptr, (float*)nullptr);
    hipLaunchKernelGGL((gemm_kernel<4, 8>), gridGemm, blk, 0, stream,
                       h1, 128, wl2s, bl2, 0, hlin, 128, N,
                       (const float*)nullptr, (const float*)nullptr, (float*)nullptr, (float*)nullptr,
                       (const float*)nullptr, (const float*)nullptr, (float*)nullptr);
    // --- layer 2 aggregation -> z[:, 0:128] (stride 288, NO relu) + z-fill ---
    hipLaunchKernelGGL(gat_edge_kernel, gridWave, blk, 0, stream,
                       row_ptr, colidx, asrc, adst, hgat, hlin, b2, 0, zbuf, 288, N,
                       ctrl, pert_table, pert);
    // --- MLP (both layers fused into one gemm) ---
    hipLaunchKernelGGL((gemm_kernel<9, 4>), gridGemm, blk, 0, stream,
                       zbuf, 288, wm1s, bm1, 1, (bf16*)nullptr, 0, N,
                       (const float*)nullptr, (const float*)nullptr, (float*)nullptr, (float*)nullptr,
                       Wm2, bm2, out);
}